// Round 2
// baseline (2341.365 us; speedup 1.0000x reference)
//
#include <hip/hip_runtime.h>

// ---------------------------------------------------------------------------
// GCNPredictor: 3x (GEMM -> weighted scatter-add (GCN norm) -> BN -> ReLU)
// then 2-row head.  N=50000 nodes, E=800000 edges, D=H=128, fp32 throughout.
//
// Workspace layout (floats):
//   hw   [N*128]  : GEMM output (messages source)
//   hbuf [N*128]  : aggregation buffer / layer activations (in-place BN+ReLU)
//   dinv [N]      : deg -> rsqrt(deg)
//   stats[256]    : per-column sum / sumsq accumulators
//   ab   [256]    : folded BN affine A (scale), B (shift)
// Total ~51.4 MB.
// ---------------------------------------------------------------------------

__global__ __launch_bounds__(256) void k_deg_init(float* deg, int n) {
  int i = blockIdx.x * 256 + threadIdx.x;
  if (i < n) deg[i] = 1.0f;  // self-loop weight
}

__global__ __launch_bounds__(256) void k_deg_edges(const int* __restrict__ col,
                                                   const float* __restrict__ w,
                                                   float* deg, int e) {
  int i = blockIdx.x * 256 + threadIdx.x;
  if (i < e) unsafeAtomicAdd(&deg[col[i]], w[i]);
}

__global__ __launch_bounds__(256) void k_dinv(float* deg, int n) {
  int i = blockIdx.x * 256 + threadIdx.x;
  if (i < n) {
    float d = deg[i];
    deg[i] = d > 0.f ? rsqrtf(d) : 0.f;
  }
}

// C[n x 128] = A[n x 128] * W[128 x 128]   (W row-major: W[k*128 + j])
// Block: 256 threads, 32 rows x 128 cols per block.
// LDS: A-tile (16 KB) + half of W at a time (32 KB) = 48 KB.
__global__ __launch_bounds__(256) void k_gemm(const float* __restrict__ A,
                                              const float* __restrict__ W,
                                              float* __restrict__ C, int n) {
  __shared__ float Ws[64 * 128];    // 32 KB (one half of W)
  __shared__ float As[32][128];     // 16 KB
  int t = threadIdx.x;
  int row0 = blockIdx.x * 32;
  int nr = min(32, n - row0);
  {
    const float4* src = (const float4*)(A + (size_t)row0 * 128);
    float4* dst = (float4*)As;
#pragma unroll
    for (int i = 0; i < 4; ++i) {
      int idx = t + 256 * i;
      int r = idx >> 5;  // 32 float4 per row
      dst[idx] = (r < nr) ? src[idx] : make_float4(0.f, 0.f, 0.f, 0.f);
    }
  }

  int c = (t & 31) * 4;   // column quad
  int rg = t >> 5;        // row group 0..7 -> rows rg, rg+8, rg+16, rg+24
  float4 a0 = {0.f, 0.f, 0.f, 0.f}, a1 = a0, a2 = a0, a3 = a0;

  for (int kh = 0; kh < 2; ++kh) {
    __syncthreads();  // As ready (iter 0) / previous Ws consumed (iter 1)
    {
      const float4* src = (const float4*)(W + (size_t)kh * 64 * 128);
      float4* dst = (float4*)Ws;
#pragma unroll
      for (int i = 0; i < 8; ++i) dst[t + 256 * i] = src[t + 256 * i];
    }
    __syncthreads();
#pragma unroll 8
    for (int k = 0; k < 64; ++k) {
      float4 w = *(const float4*)(Ws + k * 128 + c);
      int kk = kh * 64 + k;
      float h0 = As[rg][kk], h1 = As[rg + 8][kk], h2 = As[rg + 16][kk], h3 = As[rg + 24][kk];
      a0.x = fmaf(h0, w.x, a0.x); a0.y = fmaf(h0, w.y, a0.y);
      a0.z = fmaf(h0, w.z, a0.z); a0.w = fmaf(h0, w.w, a0.w);
      a1.x = fmaf(h1, w.x, a1.x); a1.y = fmaf(h1, w.y, a1.y);
      a1.z = fmaf(h1, w.z, a1.z); a1.w = fmaf(h1, w.w, a1.w);
      a2.x = fmaf(h2, w.x, a2.x); a2.y = fmaf(h2, w.y, a2.y);
      a2.z = fmaf(h2, w.z, a2.z); a2.w = fmaf(h2, w.w, a2.w);
      a3.x = fmaf(h3, w.x, a3.x); a3.y = fmaf(h3, w.y, a3.y);
      a3.z = fmaf(h3, w.z, a3.z); a3.w = fmaf(h3, w.w, a3.w);
    }
  }
  int r;
  r = row0 + rg;      if (r < n) *(float4*)(C + (size_t)r * 128 + c) = a0;
  r = row0 + rg + 8;  if (r < n) *(float4*)(C + (size_t)r * 128 + c) = a1;
  r = row0 + rg + 16; if (r < n) *(float4*)(C + (size_t)r * 128 + c) = a2;
  r = row0 + rg + 24; if (r < n) *(float4*)(C + (size_t)r * 128 + c) = a3;
}

// agg[i][:] = hw[i][:] * dinv[i]^2  (self-loop term); block 0 also zeroes stats
__global__ __launch_bounds__(256) void k_agg_init(const float* __restrict__ hw,
                                                  const float* __restrict__ dinv,
                                                  float* __restrict__ agg,
                                                  float* stats, int n) {
  if (blockIdx.x == 0 && threadIdx.x < 256) stats[threadIdx.x] = 0.f;
  int idx = blockIdx.x * 256 + threadIdx.x;  // float4 index
  if (idx < n * 32) {
    int r = idx >> 5;
    float s = dinv[r];
    s *= s;
    float4 v = ((const float4*)hw)[idx];
    v.x *= s; v.y *= s; v.z *= s; v.w *= s;
    ((float4*)agg)[idx] = v;
  }
}

// One wave (64 lanes) per edge, 4 edges per block. 2 floats/lane.
__global__ __launch_bounds__(256) void k_edge_agg(const float* __restrict__ hw,
                                                  const int* __restrict__ row,
                                                  const int* __restrict__ col,
                                                  const float* __restrict__ w,
                                                  const float* __restrict__ dinv,
                                                  float* __restrict__ agg, int e) {
  int ei = blockIdx.x * 4 + (threadIdx.x >> 6);
  int lane = threadIdx.x & 63;
  if (ei >= e) return;
  int r = row[ei], c = col[ei];
  float coeff = dinv[r] * w[ei] * dinv[c];
  float2 v = ((const float2*)(hw + (size_t)r * 128))[lane];
  float* dst = agg + (size_t)c * 128 + 2 * lane;
  unsafeAtomicAdd(dst,     v.x * coeff);
  unsafeAtomicAdd(dst + 1, v.y * coeff);
}

// Per-column sum & sumsq partials -> atomic into stats[0:128], stats[128:256]
__global__ __launch_bounds__(256) void k_bn_stats(const float* __restrict__ h,
                                                  float* stats, int n) {
  int c = threadIdx.x & 127;
  int half = threadIdx.x >> 7;
  float s = 0.f, ss = 0.f;
  for (int r = blockIdx.x * 2 + half; r < n; r += gridDim.x * 2) {
    float v = h[(size_t)r * 128 + c];
    s += v;
    ss = fmaf(v, v, ss);
  }
  __shared__ float red[256];
  red[threadIdx.x] = s;
  __syncthreads();
  if (threadIdx.x < 128) unsafeAtomicAdd(&stats[c], red[c] + red[c + 128]);
  __syncthreads();
  red[threadIdx.x] = ss;
  __syncthreads();
  if (threadIdx.x < 128) unsafeAtomicAdd(&stats[128 + c], red[c] + red[c + 128]);
}

// Fold BN into affine: A = g*istd, B = be - mu*g*istd
__global__ __launch_bounds__(128) void k_bn_finalize(const float* __restrict__ stats,
                                                     const float* __restrict__ g,
                                                     const float* __restrict__ be,
                                                     float* ab, int n) {
  int c = threadIdx.x;
  float inv_n = 1.0f / (float)n;
  float mu = stats[c] * inv_n;
  float var = stats[128 + c] * inv_n - mu * mu;
  float istd = rsqrtf(var + 1e-5f);
  float A = g[c] * istd;
  ab[c] = A;
  ab[128 + c] = fmaf(-mu, A, be[c]);
}

// h = relu(h*A + B), in place
__global__ __launch_bounds__(256) void k_bn_relu(float* __restrict__ h,
                                                 const float* __restrict__ ab, int n) {
  int idx = blockIdx.x * 256 + threadIdx.x;  // float4 index
  if (idx >= n * 32) return;
  int c4 = idx & 31;
  float4 v = ((float4*)h)[idx];
  float4 A = ((const float4*)ab)[c4];
  float4 B = ((const float4*)(ab + 128))[c4];
  v.x = fmaxf(fmaf(v.x, A.x, B.x), 0.f);
  v.y = fmaxf(fmaf(v.y, A.y, B.y), 0.f);
  v.z = fmaxf(fmaf(v.z, A.z, B.z), 0.f);
  v.w = fmaxf(fmaf(v.w, A.w, B.w), 0.f);
  ((float4*)h)[idx] = v;
}

// Final head: rows 0,1 -> relu(h@Wh + bh) -> dot with Wa / Wz
__global__ __launch_bounds__(256) void k_head(const float* __restrict__ h,
                                              const float* __restrict__ Wh,
                                              const float* __restrict__ bh,
                                              const float* __restrict__ Wa,
                                              const float* __restrict__ ba,
                                              const float* __restrict__ Wz,
                                              const float* __restrict__ bz,
                                              float* __restrict__ out) {
  __shared__ float hrow[256];
  __shared__ float red[256];
  int t = threadIdx.x;
  hrow[t] = h[t];  // rows 0 and 1 are the first 256 floats
  __syncthreads();
  int j = t & 127, r = t >> 7;
  float acc = bh[j];
  for (int k = 0; k < 128; ++k)
    acc = fmaf(hrow[r * 128 + k], Wh[k * 128 + j], acc);
  float hv = fmaxf(acc, 0.f);
  float wv = (r == 0) ? Wa[j] : Wz[j];
  red[t] = hv * wv;
  __syncthreads();
  for (int s = 64; s >= 1; s >>= 1) {
    if (j < s) red[t] += red[t + s];
    __syncthreads();
  }
  if (t == 0) out[0] = red[0] + ba[0];
  if (t == 128) out[1] = red[128] + bz[0];
}

extern "C" void kernel_launch(void* const* d_in, const int* in_sizes, int n_in,
                              void* d_out, int out_size, void* d_ws, size_t ws_size,
                              hipStream_t stream) {
  const float* x  = (const float*)d_in[0];
  const int*   ei = (const int*)d_in[1];
  const float* ew = (const float*)d_in[2];
  const float* W[3]  = {(const float*)d_in[3], (const float*)d_in[5], (const float*)d_in[7]};
  // b1/b2/b3 (d_in[4,6,8]) cancel inside BatchNorm -> skipped.
  const float* g[3]  = {(const float*)d_in[9],  (const float*)d_in[11], (const float*)d_in[13]};
  const float* be[3] = {(const float*)d_in[10], (const float*)d_in[12], (const float*)d_in[14]};
  const float* Wh = (const float*)d_in[15];
  const float* bh = (const float*)d_in[16];
  const float* Wa = (const float*)d_in[17];
  const float* ba = (const float*)d_in[18];
  const float* Wz = (const float*)d_in[19];
  const float* bz = (const float*)d_in[20];

  const int n = in_sizes[0] / 128;
  const int e = in_sizes[1] / 2;
  const int* row = ei;
  const int* col = ei + e;

  float* ws    = (float*)d_ws;
  float* hw    = ws;
  float* hbuf  = hw + (size_t)n * 128;
  float* dinv  = hbuf + (size_t)n * 128;
  float* stats = dinv + n;
  float* ab    = stats + 256;

  const int nb_n  = (n + 255) / 256;
  const int nb_e  = (e + 255) / 256;
  const int nb_f4 = (n * 32 + 255) / 256;

  k_deg_init<<<nb_n, 256, 0, stream>>>(dinv, n);
  k_deg_edges<<<nb_e, 256, 0, stream>>>(col, ew, dinv, e);
  k_dinv<<<nb_n, 256, 0, stream>>>(dinv, n);

  for (int l = 0; l < 3; ++l) {
    const float* hin = (l == 0) ? x : hbuf;
    k_gemm<<<(n + 31) / 32, 256, 0, stream>>>(hin, W[l], hw, n);
    k_agg_init<<<nb_f4, 256, 0, stream>>>(hw, dinv, hbuf, stats, n);
    k_edge_agg<<<(e + 3) / 4, 256, 0, stream>>>(hw, row, col, ew, dinv, hbuf, e);
    k_bn_stats<<<512, 256, 0, stream>>>(hbuf, stats, n);
    k_bn_finalize<<<1, 128, 0, stream>>>(stats, g[l], be[l], ab, n);
    k_bn_relu<<<nb_f4, 256, 0, stream>>>(hbuf, ab, n);
  }
  k_head<<<1, 256, 0, stream>>>(hbuf, Wh, bh, Wa, ba, Wz, bz, (float*)d_out);
}

// Round 3
// 736.166 us; speedup vs baseline: 3.1805x; 3.1805x over previous
//
#include <hip/hip_runtime.h>

// ---------------------------------------------------------------------------
// GCNPredictor: 3x (GEMM -> GCN-normalized aggregation -> BN -> ReLU) + head.
// N=50000, E=800000, D=H=128, fp32.
//
// Round-3 change: push-scatter (102M f32 atomics, 819 MB HBM writes/layer)
// replaced by CSC build + pull-gather (writes each output row exactly once).
//
// Workspace (floats unless noted):
//   hw    [N*128]  GEMM output (message source rows)
//   hbuf  [N*128]  aggregation output / activations (in-place BN+ReLU)
//   dinv  [N]      rsqrt(weighted degree incl. self-loop)
//   stats [256]    per-column sum / sumsq
//   ab    [256]    folded BN affine A,B
//   cnt   [N] int  incoming-edge counts
//   ptr   [N+1]int CSC offsets
//   cur   [N] int  fill cursors
//   esrc  [E] int  CSC: source row per edge
//   ecoef [E]      CSC: dinv[r]*w*dinv[c] per edge
// Total ~58.6 MB.
// ---------------------------------------------------------------------------

__global__ __launch_bounds__(256) void k_deg_init(float* deg, int* cnt, int n) {
  int i = blockIdx.x * 256 + threadIdx.x;
  if (i < n) { deg[i] = 1.0f; cnt[i] = 0; }  // self-loop weight 1
}

// weighted degree (float) + incoming-edge count (int), both per target col
__global__ __launch_bounds__(256) void k_deg_count(const int* __restrict__ col,
                                                   const float* __restrict__ w,
                                                   float* deg, int* cnt, int e) {
  int i = blockIdx.x * 256 + threadIdx.x;
  if (i < e) {
    int c = col[i];
    unsafeAtomicAdd(&deg[c], w[i]);
    atomicAdd(&cnt[c], 1);
  }
}

__global__ __launch_bounds__(256) void k_dinv(float* deg, int n) {
  int i = blockIdx.x * 256 + threadIdx.x;
  if (i < n) {
    float d = deg[i];
    deg[i] = d > 0.f ? rsqrtf(d) : 0.f;
  }
}

// Single-block exclusive scan of cnt -> ptr[0..n], cur[i]=ptr[i].
__global__ __launch_bounds__(1024) void k_scan(const int* __restrict__ cnt,
                                               int* __restrict__ ptr,
                                               int* __restrict__ cur, int n) {
  __shared__ int part[1024];
  int t = threadIdx.x;
  const int chunk = (n + 1023) / 1024;
  int lo = min(t * chunk, n), hi = min(lo + chunk, n);
  int s = 0;
  for (int i = lo; i < hi; ++i) s += cnt[i];
  part[t] = s;
  __syncthreads();
  for (int d = 1; d < 1024; d <<= 1) {   // Hillis-Steele inclusive scan
    int v = (t >= d) ? part[t - d] : 0;
    __syncthreads();
    part[t] += v;
    __syncthreads();
  }
  int run = (t == 0) ? 0 : part[t - 1];  // exclusive prefix
  for (int i = lo; i < hi; ++i) {
    ptr[i] = run;
    cur[i] = run;
    run += cnt[i];
  }
  if (t == 1023) ptr[n] = part[1023];
}

// Fill CSC: per edge store source row + full coefficient.
__global__ __launch_bounds__(256) void k_fill(const int* __restrict__ row,
                                              const int* __restrict__ col,
                                              const float* __restrict__ w,
                                              const float* __restrict__ dinv,
                                              int* __restrict__ cur,
                                              int* __restrict__ esrc,
                                              float* __restrict__ ecoef, int e) {
  int i = blockIdx.x * 256 + threadIdx.x;
  if (i < e) {
    int r = row[i], c = col[i];
    int pos = atomicAdd(&cur[c], 1);
    esrc[pos] = r;
    ecoef[pos] = dinv[r] * w[i] * dinv[c];
  }
}

// C[n x 128] = A[n x 128] * W[128 x 128]   (W row-major)
// 256 threads = 32 rows x 128 cols per block; 48 KB LDS (A-tile + W half).
__global__ __launch_bounds__(256) void k_gemm(const float* __restrict__ A,
                                              const float* __restrict__ W,
                                              float* __restrict__ C, int n) {
  __shared__ float Ws[64 * 128];
  __shared__ float As[32][128];
  int t = threadIdx.x;
  int row0 = blockIdx.x * 32;
  int nr = min(32, n - row0);
  {
    const float4* src = (const float4*)(A + (size_t)row0 * 128);
    float4* dst = (float4*)As;
#pragma unroll
    for (int i = 0; i < 4; ++i) {
      int idx = t + 256 * i;
      int r = idx >> 5;
      dst[idx] = (r < nr) ? src[idx] : make_float4(0.f, 0.f, 0.f, 0.f);
    }
  }
  int c = (t & 31) * 4;
  int rg = t >> 5;
  float4 a0 = {0.f, 0.f, 0.f, 0.f}, a1 = a0, a2 = a0, a3 = a0;
  for (int kh = 0; kh < 2; ++kh) {
    __syncthreads();
    {
      const float4* src = (const float4*)(W + (size_t)kh * 64 * 128);
      float4* dst = (float4*)Ws;
#pragma unroll
      for (int i = 0; i < 8; ++i) dst[t + 256 * i] = src[t + 256 * i];
    }
    __syncthreads();
#pragma unroll 8
    for (int k = 0; k < 64; ++k) {
      float4 w = *(const float4*)(Ws + k * 128 + c);
      int kk = kh * 64 + k;
      float h0 = As[rg][kk], h1 = As[rg + 8][kk], h2 = As[rg + 16][kk], h3 = As[rg + 24][kk];
      a0.x = fmaf(h0, w.x, a0.x); a0.y = fmaf(h0, w.y, a0.y);
      a0.z = fmaf(h0, w.z, a0.z); a0.w = fmaf(h0, w.w, a0.w);
      a1.x = fmaf(h1, w.x, a1.x); a1.y = fmaf(h1, w.y, a1.y);
      a1.z = fmaf(h1, w.z, a1.z); a1.w = fmaf(h1, w.w, a1.w);
      a2.x = fmaf(h2, w.x, a2.x); a2.y = fmaf(h2, w.y, a2.y);
      a2.z = fmaf(h2, w.z, a2.z); a2.w = fmaf(h2, w.w, a2.w);
      a3.x = fmaf(h3, w.x, a3.x); a3.y = fmaf(h3, w.y, a3.y);
      a3.z = fmaf(h3, w.z, a3.z); a3.w = fmaf(h3, w.w, a3.w);
    }
  }
  int r;
  r = row0 + rg;      if (r < n) *(float4*)(C + (size_t)r * 128 + c) = a0;
  r = row0 + rg + 8;  if (r < n) *(float4*)(C + (size_t)r * 128 + c) = a1;
  r = row0 + rg + 16; if (r < n) *(float4*)(C + (size_t)r * 128 + c) = a2;
  r = row0 + rg + 24; if (r < n) *(float4*)(C + (size_t)r * 128 + c) = a3;
}

// Pull-gather: one wave per destination node; lane owns 2 columns (float2).
// acc init = self-loop term; loop incoming CSC edges; single coalesced write.
__global__ __launch_bounds__(256) void k_gather(const float* __restrict__ hw,
                                                const int* __restrict__ ptr,
                                                const int* __restrict__ esrc,
                                                const float* __restrict__ ecoef,
                                                const float* __restrict__ dinv,
                                                float* __restrict__ out,
                                                float* stats, int n) {
  if (blockIdx.x == 0 && threadIdx.x < 256) stats[threadIdx.x] = 0.f;
  int node = blockIdx.x * 4 + (threadIdx.x >> 6);
  if (node >= n) return;
  int lane = threadIdx.x & 63;
  float di = dinv[node];
  float2 acc = ((const float2*)(hw + (size_t)node * 128))[lane];
  acc.x *= di * di;
  acc.y *= di * di;
  int j = ptr[node], end = ptr[node + 1];
  // 2-deep manual pipeline on the (uniform) edge metadata
  for (; j + 1 < end; j += 2) {
    int r0 = esrc[j], r1 = esrc[j + 1];
    float c0 = ecoef[j], c1 = ecoef[j + 1];
    float2 v0 = ((const float2*)(hw + (size_t)r0 * 128))[lane];
    float2 v1 = ((const float2*)(hw + (size_t)r1 * 128))[lane];
    acc.x = fmaf(v0.x, c0, acc.x); acc.y = fmaf(v0.y, c0, acc.y);
    acc.x = fmaf(v1.x, c1, acc.x); acc.y = fmaf(v1.y, c1, acc.y);
  }
  if (j < end) {
    int r0 = esrc[j];
    float c0 = ecoef[j];
    float2 v0 = ((const float2*)(hw + (size_t)r0 * 128))[lane];
    acc.x = fmaf(v0.x, c0, acc.x); acc.y = fmaf(v0.y, c0, acc.y);
  }
  ((float2*)(out + (size_t)node * 128))[lane] = acc;
}

// Per-column sum & sumsq partials -> atomics into stats[0:128], stats[128:256]
__global__ __launch_bounds__(256) void k_bn_stats(const float* __restrict__ h,
                                                  float* stats, int n) {
  int c = threadIdx.x & 127;
  int half = threadIdx.x >> 7;
  float s = 0.f, ss = 0.f;
  for (int r = blockIdx.x * 2 + half; r < n; r += gridDim.x * 2) {
    float v = h[(size_t)r * 128 + c];
    s += v;
    ss = fmaf(v, v, ss);
  }
  __shared__ float red[256];
  red[threadIdx.x] = s;
  __syncthreads();
  if (threadIdx.x < 128) unsafeAtomicAdd(&stats[c], red[c] + red[c + 128]);
  __syncthreads();
  red[threadIdx.x] = ss;
  __syncthreads();
  if (threadIdx.x < 128) unsafeAtomicAdd(&stats[128 + c], red[c] + red[c + 128]);
}

__global__ __launch_bounds__(128) void k_bn_finalize(const float* __restrict__ stats,
                                                     const float* __restrict__ g,
                                                     const float* __restrict__ be,
                                                     float* ab, int n) {
  int c = threadIdx.x;
  float inv_n = 1.0f / (float)n;
  float mu = stats[c] * inv_n;
  float var = stats[128 + c] * inv_n - mu * mu;
  float istd = rsqrtf(var + 1e-5f);
  float A = g[c] * istd;
  ab[c] = A;
  ab[128 + c] = fmaf(-mu, A, be[c]);
}

__global__ __launch_bounds__(256) void k_bn_relu(float* __restrict__ h,
                                                 const float* __restrict__ ab, int n) {
  int idx = blockIdx.x * 256 + threadIdx.x;  // float4 index
  if (idx >= n * 32) return;
  int c4 = idx & 31;
  float4 v = ((float4*)h)[idx];
  float4 A = ((const float4*)ab)[c4];
  float4 B = ((const float4*)(ab + 128))[c4];
  v.x = fmaxf(fmaf(v.x, A.x, B.x), 0.f);
  v.y = fmaxf(fmaf(v.y, A.y, B.y), 0.f);
  v.z = fmaxf(fmaf(v.z, A.z, B.z), 0.f);
  v.w = fmaxf(fmaf(v.w, A.w, B.w), 0.f);
  ((float4*)h)[idx] = v;
}

__global__ __launch_bounds__(256) void k_head(const float* __restrict__ h,
                                              const float* __restrict__ Wh,
                                              const float* __restrict__ bh,
                                              const float* __restrict__ Wa,
                                              const float* __restrict__ ba,
                                              const float* __restrict__ Wz,
                                              const float* __restrict__ bz,
                                              float* __restrict__ out) {
  __shared__ float hrow[256];
  __shared__ float red[256];
  int t = threadIdx.x;
  hrow[t] = h[t];
  __syncthreads();
  int j = t & 127, r = t >> 7;
  float acc = bh[j];
  for (int k = 0; k < 128; ++k)
    acc = fmaf(hrow[r * 128 + k], Wh[k * 128 + j], acc);
  float hv = fmaxf(acc, 0.f);
  float wv = (r == 0) ? Wa[j] : Wz[j];
  red[t] = hv * wv;
  __syncthreads();
  for (int s = 64; s >= 1; s >>= 1) {
    if (j < s) red[t] += red[t + s];
    __syncthreads();
  }
  if (t == 0) out[0] = red[0] + ba[0];
  if (t == 128) out[1] = red[128] + bz[0];
}

extern "C" void kernel_launch(void* const* d_in, const int* in_sizes, int n_in,
                              void* d_out, int out_size, void* d_ws, size_t ws_size,
                              hipStream_t stream) {
  const float* x  = (const float*)d_in[0];
  const int*   ei = (const int*)d_in[1];
  const float* ew = (const float*)d_in[2];
  const float* W[3]  = {(const float*)d_in[3], (const float*)d_in[5], (const float*)d_in[7]};
  // b1/b2/b3 cancel inside BatchNorm -> skipped.
  const float* g[3]  = {(const float*)d_in[9],  (const float*)d_in[11], (const float*)d_in[13]};
  const float* be[3] = {(const float*)d_in[10], (const float*)d_in[12], (const float*)d_in[14]};
  const float* Wh = (const float*)d_in[15];
  const float* bh = (const float*)d_in[16];
  const float* Wa = (const float*)d_in[17];
  const float* ba = (const float*)d_in[18];
  const float* Wz = (const float*)d_in[19];
  const float* bz = (const float*)d_in[20];

  const int n = in_sizes[0] / 128;
  const int e = in_sizes[1] / 2;
  const int* row = ei;
  const int* col = ei + e;

  float* ws    = (float*)d_ws;
  float* hw    = ws;
  float* hbuf  = hw + (size_t)n * 128;
  float* dinv  = hbuf + (size_t)n * 128;
  float* stats = dinv + n;
  float* ab    = stats + 256;
  int*   cnt   = (int*)(ab + 256);
  int*   ptr   = cnt + n;
  int*   cur   = ptr + n + 1;
  int*   esrc  = cur + n;
  float* ecoef = (float*)(esrc + e);

  const int nb_n  = (n + 255) / 256;
  const int nb_e  = (e + 255) / 256;
  const int nb_f4 = (n * 32 + 255) / 256;

  k_deg_init<<<nb_n, 256, 0, stream>>>(dinv, cnt, n);
  k_deg_count<<<nb_e, 256, 0, stream>>>(col, ew, dinv, cnt, e);
  k_dinv<<<nb_n, 256, 0, stream>>>(dinv, n);
  k_scan<<<1, 1024, 0, stream>>>(cnt, ptr, cur, n);
  k_fill<<<nb_e, 256, 0, stream>>>(row, col, ew, dinv, cur, esrc, ecoef, e);

  for (int l = 0; l < 3; ++l) {
    const float* hin = (l == 0) ? x : hbuf;
    k_gemm<<<(n + 31) / 32, 256, 0, stream>>>(hin, W[l], hw, n);
    k_gather<<<(n + 3) / 4, 256, 0, stream>>>(hw, ptr, esrc, ecoef, dinv, hbuf, stats, n);
    k_bn_stats<<<512, 256, 0, stream>>>(hbuf, stats, n);
    k_bn_finalize<<<1, 128, 0, stream>>>(stats, g[l], be[l], ab, n);
    k_bn_relu<<<nb_f4, 256, 0, stream>>>(hbuf, ab, n);
  }
  k_head<<<1, 256, 0, stream>>>(hbuf, Wh, bh, Wa, ba, Wz, bz, (float*)d_out);
}

// Round 4
// 591.994 us; speedup vs baseline: 3.9551x; 1.2435x over previous
//
#include <hip/hip_runtime.h>

// ---------------------------------------------------------------------------
// GCNPredictor: 3x (GEMM -> GCN aggregation -> BN -> ReLU) + 2-row head.
// N=50000, E=800000, D=H=128, fp32.
//
// Round-4: multi-block scan (was 111us single-block), BN+ReLU folded into the
// next GEMM's A-load (3x 51MB passes removed), CSC meta packed as int2.
//
// Workspace (floats unless noted):
//   hw    [N*128]   GEMM output (message source rows)
//   hbuf  [N*128]   aggregation output (raw conv out, pre-BN)
//   dinv  [N]       rsqrt(weighted degree incl. self-loop)
//   stats [256]     per-column sum / sumsq
//   ab    [3*256]   per-layer folded BN affine A,B
//   cnt   [N] int   incoming-edge counts
//   ptr   [N+1] int CSC offsets
//   cur   [N] int   fill cursors
//   bsum  [256] int scan block sums
//   emeta [E] int2  CSC: (source row, coef bits) per edge
// ---------------------------------------------------------------------------

__global__ __launch_bounds__(256) void k_deg_init(float* deg, int* cnt, int n) {
  int i = blockIdx.x * 256 + threadIdx.x;
  if (i < n) { deg[i] = 1.0f; cnt[i] = 0; }  // self-loop weight 1
}

__global__ __launch_bounds__(256) void k_deg_count(const int* __restrict__ col,
                                                   const float* __restrict__ w,
                                                   float* deg, int* cnt, int e) {
  int i = blockIdx.x * 256 + threadIdx.x;
  if (i < e) {
    int c = col[i];
    unsafeAtomicAdd(&deg[c], w[i]);
    atomicAdd(&cnt[c], 1);
  }
}

__global__ __launch_bounds__(256) void k_dinv(float* deg, int n) {
  int i = blockIdx.x * 256 + threadIdx.x;
  if (i < n) {
    float d = deg[i];
    deg[i] = d > 0.f ? rsqrtf(d) : 0.f;
  }
}

// --- 3-kernel exclusive scan of cnt[n] -> ptr[n+1], cur[i]=ptr[i] ----------
__global__ __launch_bounds__(256) void k_scan1(const int* __restrict__ cnt,
                                               int* __restrict__ ptr,
                                               int* __restrict__ bsum, int n) {
  __shared__ int sh[256];
  int t = threadIdx.x;
  int i = blockIdx.x * 256 + t;
  int v = (i < n) ? cnt[i] : 0;
  sh[t] = v;
  __syncthreads();
  for (int d = 1; d < 256; d <<= 1) {
    int u = (t >= d) ? sh[t - d] : 0;
    __syncthreads();
    sh[t] += u;
    __syncthreads();
  }
  if (i < n) ptr[i] = sh[t] - v;          // local exclusive
  if (t == 255) bsum[blockIdx.x] = sh[255];
}

__global__ __launch_bounds__(256) void k_scan2(int* __restrict__ bsum, int nb) {
  __shared__ int sh[256];
  int t = threadIdx.x;
  int v = (t < nb) ? bsum[t] : 0;
  sh[t] = v;
  __syncthreads();
  for (int d = 1; d < 256; d <<= 1) {
    int u = (t >= d) ? sh[t - d] : 0;
    __syncthreads();
    sh[t] += u;
    __syncthreads();
  }
  if (t < nb) bsum[t] = sh[t] - v;        // exclusive block offsets
}

__global__ __launch_bounds__(256) void k_scan3(int* __restrict__ ptr,
                                               int* __restrict__ cur,
                                               const int* __restrict__ bsum,
                                               int n, int e) {
  int i = blockIdx.x * 256 + threadIdx.x;
  if (i < n) {
    int p = ptr[i] + bsum[blockIdx.x];
    ptr[i] = p;
    cur[i] = p;
  }
  if (i == 0) ptr[n] = e;
}

// Fill CSC: per edge store (source row, coefficient) packed.
__global__ __launch_bounds__(256) void k_fill(const int* __restrict__ row,
                                              const int* __restrict__ col,
                                              const float* __restrict__ w,
                                              const float* __restrict__ dinv,
                                              int* __restrict__ cur,
                                              int2* __restrict__ emeta, int e) {
  int i = blockIdx.x * 256 + threadIdx.x;
  if (i < e) {
    int r = row[i], c = col[i];
    int pos = atomicAdd(&cur[c], 1);
    float coef = dinv[r] * w[i] * dinv[c];
    emeta[pos] = make_int2(r, __float_as_int(coef));
  }
}

// C[n x 128] = act(A)[n x 128] * W[128 x 128]   (W row-major)
// act = identity if ab==null, else relu(v*A + B) (folded BN of prev layer).
// 256 threads = 32 rows x 128 cols per block; 48 KB LDS.
__global__ __launch_bounds__(256) void k_gemm(const float* __restrict__ A,
                                              const float* __restrict__ W,
                                              float* __restrict__ C,
                                              const float* __restrict__ ab, int n) {
  __shared__ float Ws[64 * 128];
  __shared__ float As[32][128];
  int t = threadIdx.x;
  int row0 = blockIdx.x * 32;
  int nr = min(32, n - row0);
  {
    const float4* src = (const float4*)(A + (size_t)row0 * 128);
    float4* dst = (float4*)As;
#pragma unroll
    for (int i = 0; i < 4; ++i) {
      int idx = t + 256 * i;
      int r = idx >> 5;
      float4 v = make_float4(0.f, 0.f, 0.f, 0.f);
      if (r < nr) {
        v = src[idx];
        if (ab) {
          int c4 = idx & 31;
          float4 Aa = ((const float4*)ab)[c4];
          float4 Bb = ((const float4*)(ab + 128))[c4];
          v.x = fmaxf(fmaf(v.x, Aa.x, Bb.x), 0.f);
          v.y = fmaxf(fmaf(v.y, Aa.y, Bb.y), 0.f);
          v.z = fmaxf(fmaf(v.z, Aa.z, Bb.z), 0.f);
          v.w = fmaxf(fmaf(v.w, Aa.w, Bb.w), 0.f);
        }
      }
      dst[idx] = v;
    }
  }
  int c = (t & 31) * 4;
  int rg = t >> 5;
  float4 a0 = {0.f, 0.f, 0.f, 0.f}, a1 = a0, a2 = a0, a3 = a0;
  for (int kh = 0; kh < 2; ++kh) {
    __syncthreads();
    {
      const float4* src = (const float4*)(W + (size_t)kh * 64 * 128);
      float4* dst = (float4*)Ws;
#pragma unroll
      for (int i = 0; i < 8; ++i) dst[t + 256 * i] = src[t + 256 * i];
    }
    __syncthreads();
#pragma unroll 8
    for (int k = 0; k < 64; ++k) {
      float4 w = *(const float4*)(Ws + k * 128 + c);
      int kk = kh * 64 + k;
      float h0 = As[rg][kk], h1 = As[rg + 8][kk], h2 = As[rg + 16][kk], h3 = As[rg + 24][kk];
      a0.x = fmaf(h0, w.x, a0.x); a0.y = fmaf(h0, w.y, a0.y);
      a0.z = fmaf(h0, w.z, a0.z); a0.w = fmaf(h0, w.w, a0.w);
      a1.x = fmaf(h1, w.x, a1.x); a1.y = fmaf(h1, w.y, a1.y);
      a1.z = fmaf(h1, w.z, a1.z); a1.w = fmaf(h1, w.w, a1.w);
      a2.x = fmaf(h2, w.x, a2.x); a2.y = fmaf(h2, w.y, a2.y);
      a2.z = fmaf(h2, w.z, a2.z); a2.w = fmaf(h2, w.w, a2.w);
      a3.x = fmaf(h3, w.x, a3.x); a3.y = fmaf(h3, w.y, a3.y);
      a3.z = fmaf(h3, w.z, a3.z); a3.w = fmaf(h3, w.w, a3.w);
    }
  }
  int r;
  r = row0 + rg;      if (r < n) *(float4*)(C + (size_t)r * 128 + c) = a0;
  r = row0 + rg + 8;  if (r < n) *(float4*)(C + (size_t)r * 128 + c) = a1;
  r = row0 + rg + 16; if (r < n) *(float4*)(C + (size_t)r * 128 + c) = a2;
  r = row0 + rg + 24; if (r < n) *(float4*)(C + (size_t)r * 128 + c) = a3;
}

// Pull-gather: one wave per destination node; lane owns 2 columns (float2).
__global__ __launch_bounds__(256) void k_gather(const float* __restrict__ hw,
                                                const int* __restrict__ ptr,
                                                const int2* __restrict__ emeta,
                                                const float* __restrict__ dinv,
                                                float* __restrict__ out,
                                                float* stats, int n) {
  if (blockIdx.x == 0 && threadIdx.x < 256) stats[threadIdx.x] = 0.f;
  int node = blockIdx.x * 4 + (threadIdx.x >> 6);
  if (node >= n) return;
  int lane = threadIdx.x & 63;
  float di = dinv[node];
  float2 acc = ((const float2*)(hw + (size_t)node * 128))[lane];
  acc.x *= di * di;
  acc.y *= di * di;
  int j = ptr[node], end = ptr[node + 1];
  for (; j + 1 < end; j += 2) {
    int2 m0 = emeta[j], m1 = emeta[j + 1];
    float c0 = __int_as_float(m0.y), c1 = __int_as_float(m1.y);
    float2 v0 = ((const float2*)(hw + (size_t)m0.x * 128))[lane];
    float2 v1 = ((const float2*)(hw + (size_t)m1.x * 128))[lane];
    acc.x = fmaf(v0.x, c0, acc.x); acc.y = fmaf(v0.y, c0, acc.y);
    acc.x = fmaf(v1.x, c1, acc.x); acc.y = fmaf(v1.y, c1, acc.y);
  }
  if (j < end) {
    int2 m0 = emeta[j];
    float c0 = __int_as_float(m0.y);
    float2 v0 = ((const float2*)(hw + (size_t)m0.x * 128))[lane];
    acc.x = fmaf(v0.x, c0, acc.x); acc.y = fmaf(v0.y, c0, acc.y);
  }
  ((float2*)(out + (size_t)node * 128))[lane] = acc;
}

// Per-column sum & sumsq partials -> atomics into stats[0:128], stats[128:256]
__global__ __launch_bounds__(256) void k_bn_stats(const float* __restrict__ h,
                                                  float* stats, int n) {
  int c = threadIdx.x & 127;
  int half = threadIdx.x >> 7;
  float s = 0.f, ss = 0.f;
  for (int r = blockIdx.x * 2 + half; r < n; r += gridDim.x * 2) {
    float v = h[(size_t)r * 128 + c];
    s += v;
    ss = fmaf(v, v, ss);
  }
  __shared__ float red[256];
  red[threadIdx.x] = s;
  __syncthreads();
  if (threadIdx.x < 128) unsafeAtomicAdd(&stats[c], red[c] + red[c + 128]);
  __syncthreads();
  red[threadIdx.x] = ss;
  __syncthreads();
  if (threadIdx.x < 128) unsafeAtomicAdd(&stats[128 + c], red[c] + red[c + 128]);
}

__global__ __launch_bounds__(128) void k_bn_finalize(const float* __restrict__ stats,
                                                     const float* __restrict__ g,
                                                     const float* __restrict__ be,
                                                     float* ab, int n) {
  int c = threadIdx.x;
  float inv_n = 1.0f / (float)n;
  float mu = stats[c] * inv_n;
  float var = stats[128 + c] * inv_n - mu * mu;
  float istd = rsqrtf(var + 1e-5f);
  float A = g[c] * istd;
  ab[c] = A;
  ab[128 + c] = fmaf(-mu, A, be[c]);
}

// Head: rows 0,1 of raw conv3 out -> BN3 affine+relu -> Wh+bh -> relu -> dots
__global__ __launch_bounds__(256) void k_head(const float* __restrict__ h,
                                              const float* __restrict__ ab,
                                              const float* __restrict__ Wh,
                                              const float* __restrict__ bh,
                                              const float* __restrict__ Wa,
                                              const float* __restrict__ ba,
                                              const float* __restrict__ Wz,
                                              const float* __restrict__ bz,
                                              float* __restrict__ out) {
  __shared__ float hrow[256];
  __shared__ float red[256];
  int t = threadIdx.x;
  {
    int c = t & 127;
    hrow[t] = fmaxf(fmaf(h[t], ab[c], ab[128 + c]), 0.f);
  }
  __syncthreads();
  int j = t & 127, r = t >> 7;
  float acc = bh[j];
  for (int k = 0; k < 128; ++k)
    acc = fmaf(hrow[r * 128 + k], Wh[k * 128 + j], acc);
  float hv = fmaxf(acc, 0.f);
  float wv = (r == 0) ? Wa[j] : Wz[j];
  red[t] = hv * wv;
  __syncthreads();
  for (int s = 64; s >= 1; s >>= 1) {
    if (j < s) red[t] += red[t + s];
    __syncthreads();
  }
  if (t == 0) out[0] = red[0] + ba[0];
  if (t == 128) out[1] = red[128] + bz[0];
}

extern "C" void kernel_launch(void* const* d_in, const int* in_sizes, int n_in,
                              void* d_out, int out_size, void* d_ws, size_t ws_size,
                              hipStream_t stream) {
  const float* x  = (const float*)d_in[0];
  const int*   ei = (const int*)d_in[1];
  const float* ew = (const float*)d_in[2];
  const float* W[3]  = {(const float*)d_in[3], (const float*)d_in[5], (const float*)d_in[7]};
  // b1/b2/b3 cancel inside BatchNorm -> skipped.
  const float* g[3]  = {(const float*)d_in[9],  (const float*)d_in[11], (const float*)d_in[13]};
  const float* be[3] = {(const float*)d_in[10], (const float*)d_in[12], (const float*)d_in[14]};
  const float* Wh = (const float*)d_in[15];
  const float* bh = (const float*)d_in[16];
  const float* Wa = (const float*)d_in[17];
  const float* ba = (const float*)d_in[18];
  const float* Wz = (const float*)d_in[19];
  const float* bz = (const float*)d_in[20];

  const int n = in_sizes[0] / 128;
  const int e = in_sizes[1] / 2;
  const int* row = ei;
  const int* col = ei + e;

  float* ws    = (float*)d_ws;
  float* hw    = ws;
  float* hbuf  = hw + (size_t)n * 128;
  float* dinv  = hbuf + (size_t)n * 128;
  float* stats = dinv + n;
  float* ab    = stats + 256;          // 3 * 256
  int*   cnt   = (int*)(ab + 3 * 256);
  int*   ptr   = cnt + n;
  int*   cur   = ptr + n + 1;
  int*   bsum  = cur + n;              // 256
  int2*  emeta = (int2*)(bsum + 256);

  const int nb_n = (n + 255) / 256;
  const int nb_e = (e + 255) / 256;

  k_deg_init<<<nb_n, 256, 0, stream>>>(dinv, cnt, n);
  k_deg_count<<<nb_e, 256, 0, stream>>>(col, ew, dinv, cnt, e);
  k_dinv<<<nb_n, 256, 0, stream>>>(dinv, n);
  k_scan1<<<nb_n, 256, 0, stream>>>(cnt, ptr, bsum, n);
  k_scan2<<<1, 256, 0, stream>>>(bsum, nb_n);
  k_scan3<<<nb_n, 256, 0, stream>>>(ptr, cur, bsum, n, e);
  k_fill<<<nb_e, 256, 0, stream>>>(row, col, ew, dinv, cur, emeta, e);

  for (int l = 0; l < 3; ++l) {
    const float* hin = (l == 0) ? x : hbuf;
    const float* abp = (l == 0) ? nullptr : (ab + (l - 1) * 256);
    k_gemm<<<(n + 31) / 32, 256, 0, stream>>>(hin, W[l], hw, abp, n);
    k_gather<<<(n + 3) / 4, 256, 0, stream>>>(hw, ptr, emeta, dinv, hbuf, stats, n);
    k_bn_stats<<<512, 256, 0, stream>>>(hbuf, stats, n);
    k_bn_finalize<<<1, 128, 0, stream>>>(stats, g[l], be[l], ab + l * 256, n);
  }
  k_head<<<1, 256, 0, stream>>>(hbuf, ab + 2 * 256, Wh, bh, Wa, ba, Wz, bz,
                                (float*)d_out);
}

// Round 6
// 560.438 us; speedup vs baseline: 4.1777x; 1.0563x over previous
//
#include <hip/hip_runtime.h>

// ---------------------------------------------------------------------------
// GCNPredictor: 3x (GEMM -> GCN aggregation -> BN -> ReLU) + 2-row head.
// N=50000, E=800000, D=H=128, fp32.
//
// Round-6: resubmission of round-5 (infra container failure, no kernel
// evidence of fault). Build phase = ONE atomic per edge (rank scheme, deg
// from CSC, atomic-free fill); GEMM retiled 64 rows/block, 8r x 4c/thread,
// transposed-A LDS (broadcast b128 reads) -> 3 LDS ops per 32 FMAs.
//
// Workspace (floats unless noted):
//   hw    [N*128]   GEMM output (message source rows)
//   hbuf  [N*128]   aggregation output (raw conv out, pre-BN)
//   dinv  [N]       rsqrt(weighted degree incl. self-loop)
//   stats [256]     per-column sum / sumsq
//   ab    [3*256]   per-layer folded BN affine A,B
//   cnt   [N] int   incoming-edge counts
//   ptr   [N+1] int CSC offsets
//   bsum  [256] int scan block sums
//   rank  [E] int   per-edge within-node rank
//   emeta [E] int2  CSC: (source row, w bits -> coef bits)
// Total ~61.4 MB.
// ---------------------------------------------------------------------------

__global__ __launch_bounds__(256) void k_zero_cnt(int* cnt, int n) {
  int i = blockIdx.x * 256 + threadIdx.x;
  if (i < n) cnt[i] = 0;
}

// ONE atomic per edge: assign within-node rank, count in passing.
__global__ __launch_bounds__(256) void k_count_rank(const int* __restrict__ col,
                                                    int* __restrict__ cnt,
                                                    int* __restrict__ rank, int e) {
  int i = blockIdx.x * 256 + threadIdx.x;
  if (i < e) rank[i] = atomicAdd(&cnt[col[i]], 1);
}

// --- 3-kernel exclusive scan of cnt[n] -> ptr[n+1] -------------------------
__global__ __launch_bounds__(256) void k_scan1(const int* __restrict__ cnt,
                                               int* __restrict__ ptr,
                                               int* __restrict__ bsum, int n) {
  __shared__ int sh[256];
  int t = threadIdx.x;
  int i = blockIdx.x * 256 + t;
  int v = (i < n) ? cnt[i] : 0;
  sh[t] = v;
  __syncthreads();
  for (int d = 1; d < 256; d <<= 1) {
    int u = (t >= d) ? sh[t - d] : 0;
    __syncthreads();
    sh[t] += u;
    __syncthreads();
  }
  if (i < n) ptr[i] = sh[t] - v;          // local exclusive
  if (t == 255) bsum[blockIdx.x] = sh[255];
}

__global__ __launch_bounds__(256) void k_scan2(int* __restrict__ bsum, int nb) {
  __shared__ int sh[256];
  int t = threadIdx.x;
  int v = (t < nb) ? bsum[t] : 0;
  sh[t] = v;
  __syncthreads();
  for (int d = 1; d < 256; d <<= 1) {
    int u = (t >= d) ? sh[t - d] : 0;
    __syncthreads();
    sh[t] += u;
    __syncthreads();
  }
  if (t < nb) bsum[t] = sh[t] - v;        // exclusive block offsets
}

__global__ __launch_bounds__(256) void k_scan3(int* __restrict__ ptr,
                                               const int* __restrict__ bsum,
                                               int n, int e) {
  int i = blockIdx.x * 256 + threadIdx.x;
  if (i < n) ptr[i] += bsum[blockIdx.x];
  if (i == 0) ptr[n] = e;
}

// Atomic-free fill: slot = ptr[col] + rank. Store (source row, raw w).
__global__ __launch_bounds__(256) void k_fill(const int* __restrict__ row,
                                              const int* __restrict__ col,
                                              const float* __restrict__ w,
                                              const int* __restrict__ ptr,
                                              const int* __restrict__ rank,
                                              int2* __restrict__ emeta, int e) {
  int i = blockIdx.x * 256 + threadIdx.x;
  if (i < e) {
    int pos = ptr[col[i]] + rank[i];
    emeta[pos] = make_int2(row[i], __float_as_int(w[i]));
  }
}

// Per-node: deg = 1 (self-loop) + sum of incoming w (coalesced CSC walk).
__global__ __launch_bounds__(256) void k_deg_dinv(const int* __restrict__ ptr,
                                                  const int2* __restrict__ emeta,
                                                  float* __restrict__ dinv, int n) {
  int i = blockIdx.x * 256 + threadIdx.x;
  if (i >= n) return;
  int j = ptr[i], end = ptr[i + 1];
  float d = 1.0f;
  for (; j < end; ++j) d += __int_as_float(emeta[j].y);
  dinv[i] = rsqrtf(d);
}

// Rewrite stored w -> full coefficient dinv[r]*w*dinv[c].
__global__ __launch_bounds__(256) void k_coef(const int* __restrict__ ptr,
                                              int2* __restrict__ emeta,
                                              const float* __restrict__ dinv, int n) {
  int i = blockIdx.x * 256 + threadIdx.x;
  if (i >= n) return;
  float dc = dinv[i];
  int j = ptr[i], end = ptr[i + 1];
  for (; j < end; ++j) {
    int2 m = emeta[j];
    emeta[j] = make_int2(m.x, __float_as_int(dinv[m.x] * __int_as_float(m.y) * dc));
  }
}

// C[n x 128] = act(A)[n x 128] * W[128 x 128]   (W row-major)
// act = identity if ab==null, else relu(v*A + B) (folded BN of prev layer).
// 64 rows/block, 256 threads, 8 rows x 4 cols per thread.
// At transposed [k][row] so inner loop = 2 broadcast b128 (A) + 1 b128 (W).
__global__ __launch_bounds__(256) void k_gemm(const float* __restrict__ A,
                                              const float* __restrict__ W,
                                              float* __restrict__ C,
                                              const float* __restrict__ ab, int n) {
  __shared__ float At[128 * 64];    // transposed A-tile, 32 KB
  __shared__ float Ws[64 * 128];    // half of W, 32 KB
  int t = threadIdx.x;
  int row0 = blockIdx.x * 64;
  int nr = min(64, n - row0);
  // Stage A transposed (+BN+ReLU). Swizzle row by ((k>>2)&3)<<3 to spread
  // staging-write banks (8-way instead of 32-way); reads un-swizzle per k.
  {
    const float4* src = (const float4*)(A + (size_t)row0 * 128);
#pragma unroll
    for (int i = 0; i < 8; ++i) {
      int idx = t + 256 * i;        // 0..2047 float4s
      int r = idx >> 5;             // row 0..63
      int j4 = idx & 31;            // float4-col
      float4 v = make_float4(0.f, 0.f, 0.f, 0.f);
      if (r < nr) {
        v = src[idx];
        if (ab) {
          float4 Aa = ((const float4*)ab)[j4];
          float4 Bb = ((const float4*)(ab + 128))[j4];
          v.x = fmaxf(fmaf(v.x, Aa.x, Bb.x), 0.f);
          v.y = fmaxf(fmaf(v.y, Aa.y, Bb.y), 0.f);
          v.z = fmaxf(fmaf(v.z, Aa.z, Bb.z), 0.f);
          v.w = fmaxf(fmaf(v.w, Aa.w, Bb.w), 0.f);
        }
      }
      int k0 = j4 * 4;
      int rs = r ^ ((j4 & 3) << 3);  // ((k>>2)&3)<<3 with k=k0..k0+3 (same j4)
      At[(k0 + 0) * 64 + rs] = v.x;
      At[(k0 + 1) * 64 + rs] = v.y;
      At[(k0 + 2) * 64 + rs] = v.z;
      At[(k0 + 3) * 64 + rs] = v.w;
    }
  }
  int cg = t & 31;                  // cols cg*4..+3
  int rbase = (t >> 5) * 8;         // rows rbase..+7
  float4 acc[8];
#pragma unroll
  for (int m = 0; m < 8; ++m) acc[m] = make_float4(0.f, 0.f, 0.f, 0.f);

  for (int kh = 0; kh < 2; ++kh) {
    __syncthreads();
    {
      const float4* src = (const float4*)(W + (size_t)kh * 64 * 128);
      float4* dst = (float4*)Ws;
#pragma unroll
      for (int i = 0; i < 8; ++i) dst[t + 256 * i] = src[t + 256 * i];
    }
    __syncthreads();
#pragma unroll 4
    for (int k = 0; k < 64; ++k) {
      int kk = kh * 64 + k;
      float4 w = *(const float4*)(Ws + k * 128 + cg * 4);
      int rs = rbase ^ (((kk >> 2) & 3) << 3);
      const float* ap = At + kk * 64 + rs;
      float4 a0 = *(const float4*)ap;         // rows rbase..+3 (broadcast)
      float4 a1 = *(const float4*)(ap + 4);   // rows +4..+7   (broadcast)
      acc[0].x = fmaf(a0.x, w.x, acc[0].x); acc[0].y = fmaf(a0.x, w.y, acc[0].y);
      acc[0].z = fmaf(a0.x, w.z, acc[0].z); acc[0].w = fmaf(a0.x, w.w, acc[0].w);
      acc[1].x = fmaf(a0.y, w.x, acc[1].x); acc[1].y = fmaf(a0.y, w.y, acc[1].y);
      acc[1].z = fmaf(a0.y, w.z, acc[1].z); acc[1].w = fmaf(a0.y, w.w, acc[1].w);
      acc[2].x = fmaf(a0.z, w.x, acc[2].x); acc[2].y = fmaf(a0.z, w.y, acc[2].y);
      acc[2].z = fmaf(a0.z, w.z, acc[2].z); acc[2].w = fmaf(a0.z, w.w, acc[2].w);
      acc[3].x = fmaf(a0.w, w.x, acc[3].x); acc[3].y = fmaf(a0.w, w.y, acc[3].y);
      acc[3].z = fmaf(a0.w, w.z, acc[3].z); acc[3].w = fmaf(a0.w, w.w, acc[3].w);
      acc[4].x = fmaf(a1.x, w.x, acc[4].x); acc[4].y = fmaf(a1.x, w.y, acc[4].y);
      acc[4].z = fmaf(a1.x, w.z, acc[4].z); acc[4].w = fmaf(a1.x, w.w, acc[4].w);
      acc[5].x = fmaf(a1.y, w.x, acc[5].x); acc[5].y = fmaf(a1.y, w.y, acc[5].y);
      acc[5].z = fmaf(a1.y, w.z, acc[5].z); acc[5].w = fmaf(a1.y, w.w, acc[5].w);
      acc[6].x = fmaf(a1.z, w.x, acc[6].x); acc[6].y = fmaf(a1.z, w.y, acc[6].y);
      acc[6].z = fmaf(a1.z, w.z, acc[6].z); acc[6].w = fmaf(a1.z, w.w, acc[6].w);
      acc[7].x = fmaf(a1.w, w.x, acc[7].x); acc[7].y = fmaf(a1.w, w.y, acc[7].y);
      acc[7].z = fmaf(a1.w, w.z, acc[7].z); acc[7].w = fmaf(a1.w, w.w, acc[7].w);
    }
  }
#pragma unroll
  for (int m = 0; m < 8; ++m) {
    int r = row0 + rbase + m;
    if (r < n) *(float4*)(C + (size_t)r * 128 + cg * 4) = acc[m];
  }
}

// Pull-gather: one wave per destination node; lane owns 2 columns (float2).
__global__ __launch_bounds__(256) void k_gather(const float* __restrict__ hw,
                                                const int* __restrict__ ptr,
                                                const int2* __restrict__ emeta,
                                                const float* __restrict__ dinv,
                                                float* __restrict__ out,
                                                float* stats, int n) {
  if (blockIdx.x == 0 && threadIdx.x < 256) stats[threadIdx.x] = 0.f;
  int node = blockIdx.x * 4 + (threadIdx.x >> 6);
  if (node >= n) return;
  int lane = threadIdx.x & 63;
  float di = dinv[node];
  float2 acc = ((const float2*)(hw + (size_t)node * 128))[lane];
  acc.x *= di * di;
  acc.y *= di * di;
  int j = ptr[node], end = ptr[node + 1];
  for (; j + 1 < end; j += 2) {
    int2 m0 = emeta[j], m1 = emeta[j + 1];
    float c0 = __int_as_float(m0.y), c1 = __int_as_float(m1.y);
    float2 v0 = ((const float2*)(hw + (size_t)m0.x * 128))[lane];
    float2 v1 = ((const float2*)(hw + (size_t)m1.x * 128))[lane];
    acc.x = fmaf(v0.x, c0, acc.x); acc.y = fmaf(v0.y, c0, acc.y);
    acc.x = fmaf(v1.x, c1, acc.x); acc.y = fmaf(v1.y, c1, acc.y);
  }
  if (j < end) {
    int2 m0 = emeta[j];
    float c0 = __int_as_float(m0.y);
    float2 v0 = ((const float2*)(hw + (size_t)m0.x * 128))[lane];
    acc.x = fmaf(v0.x, c0, acc.x); acc.y = fmaf(v0.y, c0, acc.y);
  }
  ((float2*)(out + (size_t)node * 128))[lane] = acc;
}

// Per-column sum & sumsq partials -> atomics into stats[0:128], stats[128:256]
__global__ __launch_bounds__(256) void k_bn_stats(const float* __restrict__ h,
                                                  float* stats, int n) {
  int c = threadIdx.x & 127;
  int half = threadIdx.x >> 7;
  float s = 0.f, ss = 0.f;
  for (int r = blockIdx.x * 2 + half; r < n; r += gridDim.x * 2) {
    float v = h[(size_t)r * 128 + c];
    s += v;
    ss = fmaf(v, v, ss);
  }
  __shared__ float red[256];
  red[threadIdx.x] = s;
  __syncthreads();
  if (threadIdx.x < 128) unsafeAtomicAdd(&stats[c], red[c] + red[c + 128]);
  __syncthreads();
  red[threadIdx.x] = ss;
  __syncthreads();
  if (threadIdx.x < 128) unsafeAtomicAdd(&stats[128 + c], red[c] + red[c + 128]);
}

__global__ __launch_bounds__(128) void k_bn_finalize(const float* __restrict__ stats,
                                                     const float* __restrict__ g,
                                                     const float* __restrict__ be,
                                                     float* ab, int n) {
  int c = threadIdx.x;
  float inv_n = 1.0f / (float)n;
  float mu = stats[c] * inv_n;
  float var = stats[128 + c] * inv_n - mu * mu;
  float istd = rsqrtf(var + 1e-5f);
  float A = g[c] * istd;
  ab[c] = A;
  ab[128 + c] = fmaf(-mu, A, be[c]);
}

// Head: rows 0,1 of raw conv3 out -> BN3 affine+relu -> Wh+bh -> relu -> dots
__global__ __launch_bounds__(256) void k_head(const float* __restrict__ h,
                                              const float* __restrict__ ab,
                                              const float* __restrict__ Wh,
                                              const float* __restrict__ bh,
                                              const float* __restrict__ Wa,
                                              const float* __restrict__ ba,
                                              const float* __restrict__ Wz,
                                              const float* __restrict__ bz,
                                              float* __restrict__ out) {
  __shared__ float hrow[256];
  __shared__ float red[256];
  int t = threadIdx.x;
  {
    int c = t & 127;
    hrow[t] = fmaxf(fmaf(h[t], ab[c], ab[128 + c]), 0.f);
  }
  __syncthreads();
  int j = t & 127, r = t >> 7;
  float acc = bh[j];
  for (int k = 0; k < 128; ++k)
    acc = fmaf(hrow[r * 128 + k], Wh[k * 128 + j], acc);
  float hv = fmaxf(acc, 0.f);
  float wv = (r == 0) ? Wa[j] : Wz[j];
  red[t] = hv * wv;
  __syncthreads();
  for (int s = 64; s >= 1; s >>= 1) {
    if (j < s) red[t] += red[t + s];
    __syncthreads();
  }
  if (t == 0) out[0] = red[0] + ba[0];
  if (t == 128) out[1] = red[128] + bz[0];
}

extern "C" void kernel_launch(void* const* d_in, const int* in_sizes, int n_in,
                              void* d_out, int out_size, void* d_ws, size_t ws_size,
                              hipStream_t stream) {
  const float* x  = (const float*)d_in[0];
  const int*   ei = (const int*)d_in[1];
  const float* ew = (const float*)d_in[2];
  const float* W[3]  = {(const float*)d_in[3], (const float*)d_in[5], (const float*)d_in[7]};
  // b1/b2/b3 cancel inside BatchNorm -> skipped.
  const float* g[3]  = {(const float*)d_in[9],  (const float*)d_in[11], (const float*)d_in[13]};
  const float* be[3] = {(const float*)d_in[10], (const float*)d_in[12], (const float*)d_in[14]};
  const float* Wh = (const float*)d_in[15];
  const float* bh = (const float*)d_in[16];
  const float* Wa = (const float*)d_in[17];
  const float* ba = (const float*)d_in[18];
  const float* Wz = (const float*)d_in[19];
  const float* bz = (const float*)d_in[20];

  const int n = in_sizes[0] / 128;
  const int e = in_sizes[1] / 2;
  const int* row = ei;
  const int* col = ei + e;

  float* ws    = (float*)d_ws;
  float* hw    = ws;
  float* hbuf  = hw + (size_t)n * 128;
  float* dinv  = hbuf + (size_t)n * 128;
  float* stats = dinv + n;
  float* ab    = stats + 256;          // 3 * 256
  int*   cnt   = (int*)(ab + 3 * 256);
  int*   ptr   = cnt + n;
  int*   bsum  = ptr + n + 1;          // 256
  int*   rank  = bsum + 256;           // E
  int2*  emeta = (int2*)(rank + e);    // E int2

  const int nb_n = (n + 255) / 256;
  const int nb_e = (e + 255) / 256;

  k_zero_cnt<<<nb_n, 256, 0, stream>>>(cnt, n);
  k_count_rank<<<nb_e, 256, 0, stream>>>(col, cnt, rank, e);
  k_scan1<<<nb_n, 256, 0, stream>>>(cnt, ptr, bsum, n);
  k_scan2<<<1, 256, 0, stream>>>(bsum, nb_n);
  k_scan3<<<nb_n, 256, 0, stream>>>(ptr, bsum, n, e);
  k_fill<<<nb_e, 256, 0, stream>>>(row, col, ew, ptr, rank, emeta, e);
  k_deg_dinv<<<nb_n, 256, 0, stream>>>(ptr, emeta, dinv, n);
  k_coef<<<nb_n, 256, 0, stream>>>(ptr, emeta, dinv, n);

  for (int l = 0; l < 3; ++l) {
    const float* hin = (l == 0) ? x : hbuf;
    const float* abp = (l == 0) ? nullptr : (ab + (l - 1) * 256);
    k_gemm<<<(n + 63) / 64, 256, 0, stream>>>(hin, W[l], hw, abp, n);
    k_gather<<<(n + 3) / 4, 256, 0, stream>>>(hw, ptr, emeta, dinv, hbuf, stats, n);
    k_bn_stats<<<512, 256, 0, stream>>>(hbuf, stats, n);
    k_bn_finalize<<<1, 128, 0, stream>>>(stats, g[l], be[l], ab + l * 256, n);
  }
  k_head<<<1, 256, 0, stream>>>(hbuf, ab + 2 * 256, Wh, bh, Wa, ba, Wz, bz,
                                (float*)d_out);
}

// Round 8
// 487.361 us; speedup vs baseline: 4.8042x; 1.1499x over previous
//
#include <hip/hip_runtime.h>

// ---------------------------------------------------------------------------
// GCNPredictor: 3x (bf16 MFMA GEMM -> bf16 pull-gather -> BN -> ReLU) + head.
// N=50000, E=800000, D=H=128.
//
// Round-8: resubmission of round-7 (infra container failure; OOB/hang audit
// clean). Activations bf16 (halves gather traffic, the #1 cost at 200us);
// GEMM on mfma_f32_16x16x32_bf16 with XOR-swizzled LDS cells.
// All accumulations (gather, BN stats, head) remain fp32.
//
// Workspace:
//   hw_b  [N*128] u16   GEMM output (message rows, bf16)
//   hbuf_b[N*128] u16   aggregation output (pre-BN, bf16)
//   dinv  [N] f32       rsqrt(weighted degree incl self-loop)
//   stats [256] f32     per-column sum / sumsq
//   ab    [3*256] f32   per-layer folded BN affine A,B
//   cnt/ptr/bsum/rank   CSC build (int)
//   emeta [E] int2      CSC: (src row, coef bits)
// ---------------------------------------------------------------------------

typedef unsigned short u16;
typedef unsigned int u32;
typedef unsigned long long u64;
typedef short bf16x8 __attribute__((ext_vector_type(8)));
typedef float f32x4 __attribute__((ext_vector_type(4)));

__device__ inline float bf2f(u16 u) { return __uint_as_float(((u32)u) << 16); }
__device__ inline u16 f2bf(float f) {          // RTNE, finite inputs
  u32 u = __float_as_uint(f);
  return (u16)((u + 0x7FFFu + ((u >> 16) & 1u)) >> 16);
}

// ---------------- CSC build ------------------------------------------------
__global__ __launch_bounds__(256) void k_zero_cnt(int* cnt, int n) {
  int i = blockIdx.x * 256 + threadIdx.x;
  if (i < n) cnt[i] = 0;
}

__global__ __launch_bounds__(256) void k_count_rank(const int* __restrict__ col,
                                                    int* __restrict__ cnt,
                                                    int* __restrict__ rank, int e) {
  int i = blockIdx.x * 256 + threadIdx.x;
  if (i < e) rank[i] = atomicAdd(&cnt[col[i]], 1);
}

__global__ __launch_bounds__(256) void k_scan1(const int* __restrict__ cnt,
                                               int* __restrict__ ptr,
                                               int* __restrict__ bsum, int n) {
  __shared__ int sh[256];
  int t = threadIdx.x;
  int i = blockIdx.x * 256 + t;
  int v = (i < n) ? cnt[i] : 0;
  sh[t] = v;
  __syncthreads();
  for (int d = 1; d < 256; d <<= 1) {
    int u = (t >= d) ? sh[t - d] : 0;
    __syncthreads();
    sh[t] += u;
    __syncthreads();
  }
  if (i < n) ptr[i] = sh[t] - v;
  if (t == 255) bsum[blockIdx.x] = sh[255];
}

__global__ __launch_bounds__(256) void k_scan2(int* __restrict__ bsum, int nb) {
  __shared__ int sh[256];
  int t = threadIdx.x;
  int v = (t < nb) ? bsum[t] : 0;
  sh[t] = v;
  __syncthreads();
  for (int d = 1; d < 256; d <<= 1) {
    int u = (t >= d) ? sh[t - d] : 0;
    __syncthreads();
    sh[t] += u;
    __syncthreads();
  }
  if (t < nb) bsum[t] = sh[t] - v;
}

__global__ __launch_bounds__(256) void k_scan3(int* __restrict__ ptr,
                                               const int* __restrict__ bsum,
                                               int n, int e) {
  int i = blockIdx.x * 256 + threadIdx.x;
  if (i < n) ptr[i] += bsum[blockIdx.x];
  if (i == 0) ptr[n] = e;
}

__global__ __launch_bounds__(256) void k_fill(const int* __restrict__ row,
                                              const int* __restrict__ col,
                                              const float* __restrict__ w,
                                              const int* __restrict__ ptr,
                                              const int* __restrict__ rank,
                                              int2* __restrict__ emeta, int e) {
  int i = blockIdx.x * 256 + threadIdx.x;
  if (i < e) {
    int pos = ptr[col[i]] + rank[i];
    emeta[pos] = make_int2(row[i], __float_as_int(w[i]));
  }
}

__global__ __launch_bounds__(256) void k_deg_dinv(const int* __restrict__ ptr,
                                                  const int2* __restrict__ emeta,
                                                  float* __restrict__ dinv, int n) {
  int i = blockIdx.x * 256 + threadIdx.x;
  if (i >= n) return;
  int j = ptr[i], end = ptr[i + 1];
  float d = 1.0f;
  for (; j < end; ++j) d += __int_as_float(emeta[j].y);
  dinv[i] = rsqrtf(d);
}

__global__ __launch_bounds__(256) void k_coef(const int* __restrict__ ptr,
                                              int2* __restrict__ emeta,
                                              const float* __restrict__ dinv, int n) {
  int i = blockIdx.x * 256 + threadIdx.x;
  if (i >= n) return;
  float dc = dinv[i];
  int j = ptr[i], end = ptr[i + 1];
  for (; j < end; ++j) {
    int2 m = emeta[j];
    emeta[j] = make_int2(m.x, __float_as_int(dinv[m.x] * __int_as_float(m.y) * dc));
  }
}

// ---------------- bf16 MFMA GEMM -------------------------------------------
// C[n x 128](bf16) = act(A)[n x 128] * W[128 x 128]; act = BN-affine+relu of
// previous layer (ab != null) applied during staging.
// Tile 128x128, 256 threads (4 waves); wave w owns rows [w*32, w*32+32).
// LDS: A and W^T as 8-byte cells (4 bf16 along k), cell (r,k4) stored at
// [r*32 + (k4 ^ (r&15))] -> conflict-free b64 fragment reads.
// A- and B-fragments use the IDENTICAL (lane,elem)->k convention, so the
// product is invariant to the HW's internal k permutation. C/D layout:
// col = lane&15, row = (lane>>4)*4 + reg  (learn_hip m89-verified).
__global__ __launch_bounds__(256) void k_gemm(const void* __restrict__ Ain,
                                              int a_is_f32,
                                              const float* __restrict__ W,
                                              u16* __restrict__ C,
                                              const float* __restrict__ ab, int n) {
  __shared__ u64 As64[128 * 32];   // 32 KB
  __shared__ u64 Ws64[128 * 32];   // 32 KB
  int t = threadIdx.x;
  int row0 = blockIdx.x * 128;
  int nr = min(128, n - row0);

  if (a_is_f32) {                  // layer 0: fp32 input, no affine
    const float4* src = (const float4*)((const float*)Ain + (size_t)row0 * 128);
#pragma unroll
    for (int i = 0; i < 16; ++i) {
      int idx = t + 256 * i;       // float4 id within tile
      int r = idx >> 5;
      int j4 = idx & 31;           // cell k4 = j4
      float4 v = (r < nr) ? src[idx] : make_float4(0.f, 0.f, 0.f, 0.f);
      u64 cell = (u64)f2bf(v.x) | ((u64)f2bf(v.y) << 16) |
                 ((u64)f2bf(v.z) << 32) | ((u64)f2bf(v.w) << 48);
      As64[r * 32 + (j4 ^ (r & 15))] = cell;
    }
  } else {                         // bf16 input (+ optional affine+relu)
    const u16* A = (const u16*)Ain;
#pragma unroll
    for (int i = 0; i < 8; ++i) {
      int idx = t + 256 * i;       // 16B chunk id
      int r = idx >> 4;
      int c8 = idx & 15;           // 8-bf16 chunk
      u64 lo = 0, hi = 0;
      if (r < nr) {
        const u64* srcq = (const u64*)(A + ((size_t)(row0 + r)) * 128 + c8 * 8);
        lo = srcq[0]; hi = srcq[1];
        if (ab) {
          u64 nl = 0, nh = 0;
#pragma unroll
          for (int j = 0; j < 4; ++j) {
            int c = c8 * 8 + j;
            float f = fmaxf(fmaf(bf2f((u16)(lo >> (16 * j))), ab[c], ab[128 + c]), 0.f);
            nl |= ((u64)f2bf(f)) << (16 * j);
            int c2 = c + 4;
            float f2 = fmaxf(fmaf(bf2f((u16)(hi >> (16 * j))), ab[c2], ab[128 + c2]), 0.f);
            nh |= ((u64)f2bf(f2)) << (16 * j);
          }
          lo = nl; hi = nh;
        }
      }
      As64[r * 32 + ((c8 * 2) ^ (r & 15))] = lo;
      As64[r * 32 + ((c8 * 2 + 1) ^ (r & 15))] = hi;
    }
  }
  {  // stage W transposed: cell (col, k4) = W[k4*4 .. +3][col]
    int col = t & 127;
    int khalf = t >> 7;
#pragma unroll
    for (int kk = 0; kk < 16; ++kk) {
      int k4 = khalf * 16 + kk;
      int k = k4 * 4;
      u64 cell = (u64)f2bf(W[(size_t)(k + 0) * 128 + col]) |
                 ((u64)f2bf(W[(size_t)(k + 1) * 128 + col]) << 16) |
                 ((u64)f2bf(W[(size_t)(k + 2) * 128 + col]) << 32) |
                 ((u64)f2bf(W[(size_t)(k + 3) * 128 + col]) << 48);
      Ws64[col * 32 + (k4 ^ (col & 15))] = cell;
    }
  }
  __syncthreads();

  int w = t >> 6, l = t & 63;
  int lr = l & 15, kg = l >> 4;
  int rA0 = w * 32 + lr, rA1 = rA0 + 16;   // rA&15 == lr
  f32x4 acc[2][8];
#pragma unroll
  for (int m = 0; m < 2; ++m)
#pragma unroll
    for (int nf = 0; nf < 8; ++nf) acc[m][nf] = (f32x4){0.f, 0.f, 0.f, 0.f};

  union Frag { u64 q[2]; bf16x8 v; };
#pragma unroll
  for (int ks = 0; ks < 4; ++ks) {
    int kb = ks * 8 + kg;
    Frag a0, a1;
    a0.q[0] = As64[rA0 * 32 + (kb ^ lr)];
    a0.q[1] = As64[rA0 * 32 + ((kb + 4) ^ lr)];
    a1.q[0] = As64[rA1 * 32 + (kb ^ lr)];
    a1.q[1] = As64[rA1 * 32 + ((kb + 4) ^ lr)];
#pragma unroll
    for (int nf = 0; nf < 8; ++nf) {
      Frag b;
      b.q[0] = Ws64[(nf * 16 + lr) * 32 + (kb ^ lr)];
      b.q[1] = Ws64[(nf * 16 + lr) * 32 + ((kb + 4) ^ lr)];
      acc[0][nf] = __builtin_amdgcn_mfma_f32_16x16x32_bf16(a0.v, b.v, acc[0][nf], 0, 0, 0);
      acc[1][nf] = __builtin_amdgcn_mfma_f32_16x16x32_bf16(a1.v, b.v, acc[1][nf], 0, 0, 0);
    }
  }
#pragma unroll
  for (int m = 0; m < 2; ++m)
#pragma unroll
    for (int nf = 0; nf < 8; ++nf)
#pragma unroll
      for (int j = 0; j < 4; ++j) {
        int gr = row0 + w * 32 + m * 16 + kg * 4 + j;
        if (gr < n) C[(size_t)gr * 128 + nf * 16 + lr] = f2bf(acc[m][nf][j]);
      }
}

// ---------------- bf16 pull-gather -----------------------------------------
// One wave per node; lane owns 2 columns (one u32 = 2 bf16). fp32 accum.
__global__ __launch_bounds__(256) void k_gather(const u16* __restrict__ hw,
                                                const int* __restrict__ ptr,
                                                const int2* __restrict__ emeta,
                                                const float* __restrict__ dinv,
                                                u16* __restrict__ out,
                                                float* stats, int n) {
  if (blockIdx.x == 0 && threadIdx.x < 256) stats[threadIdx.x] = 0.f;
  int node = blockIdx.x * 4 + (threadIdx.x >> 6);
  if (node >= n) return;
  int lane = threadIdx.x & 63;
  float di = dinv[node];
  u32 su = ((const u32*)(hw + (size_t)node * 128))[lane];
  float ax = bf2f((u16)su) * di * di;
  float ay = bf2f((u16)(su >> 16)) * di * di;
  int j = ptr[node], end = ptr[node + 1];
  for (; j + 1 < end; j += 2) {
    int2 m0 = emeta[j], m1 = emeta[j + 1];
    float c0 = __int_as_float(m0.y), c1 = __int_as_float(m1.y);
    u32 v0 = ((const u32*)(hw + (size_t)m0.x * 128))[lane];
    u32 v1 = ((const u32*)(hw + (size_t)m1.x * 128))[lane];
    ax = fmaf(bf2f((u16)v0), c0, ax);
    ay = fmaf(bf2f((u16)(v0 >> 16)), c0, ay);
    ax = fmaf(bf2f((u16)v1), c1, ax);
    ay = fmaf(bf2f((u16)(v1 >> 16)), c1, ay);
  }
  if (j < end) {
    int2 m0 = emeta[j];
    float c0 = __int_as_float(m0.y);
    u32 v0 = ((const u32*)(hw + (size_t)m0.x * 128))[lane];
    ax = fmaf(bf2f((u16)v0), c0, ax);
    ay = fmaf(bf2f((u16)(v0 >> 16)), c0, ay);
  }
  u32 o = (u32)f2bf(ax) | ((u32)f2bf(ay) << 16);
  ((u32*)(out + (size_t)node * 128))[lane] = o;
}

// ---------------- BN stats (bf16 input, fp32 accum) ------------------------
__global__ __launch_bounds__(256) void k_bn_stats(const u16* __restrict__ h,
                                                  float* stats, int n) {
  int c2 = threadIdx.x & 63;   // u32 column (2 bf16)
  int q = threadIdx.x >> 6;    // row group 0..3
  float sx = 0.f, sy = 0.f, ssx = 0.f, ssy = 0.f;
  for (int r = blockIdx.x * 4 + q; r < n; r += gridDim.x * 4) {
    u32 u = ((const u32*)(h + (size_t)r * 128))[c2];
    float vx = bf2f((u16)u), vy = bf2f((u16)(u >> 16));
    sx += vx; sy += vy;
    ssx = fmaf(vx, vx, ssx); ssy = fmaf(vy, vy, ssy);
  }
  __shared__ float4 red[256];
  red[threadIdx.x] = make_float4(sx, sy, ssx, ssy);
  __syncthreads();
  if (q == 0) {
    float4 a = red[c2], b = red[c2 + 64], c = red[c2 + 128], d = red[c2 + 192];
    unsafeAtomicAdd(&stats[2 * c2],           a.x + b.x + c.x + d.x);
    unsafeAtomicAdd(&stats[2 * c2 + 1],       a.y + b.y + c.y + d.y);
    unsafeAtomicAdd(&stats[128 + 2 * c2],     a.z + b.z + c.z + d.z);
    unsafeAtomicAdd(&stats[128 + 2 * c2 + 1], a.w + b.w + c.w + d.w);
  }
}

__global__ __launch_bounds__(128) void k_bn_finalize(const float* __restrict__ stats,
                                                     const float* __restrict__ g,
                                                     const float* __restrict__ be,
                                                     float* ab, int n) {
  int c = threadIdx.x;
  float inv_n = 1.0f / (float)n;
  float mu = stats[c] * inv_n;
  float var = stats[128 + c] * inv_n - mu * mu;
  float istd = rsqrtf(var + 1e-5f);
  float A = g[c] * istd;
  ab[c] = A;
  ab[128 + c] = fmaf(-mu, A, be[c]);
}

// ---------------- head -----------------------------------------------------
__global__ __launch_bounds__(256) void k_head(const u16* __restrict__ h,
                                              const float* __restrict__ ab,
                                              const float* __restrict__ Wh,
                                              const float* __restrict__ bh,
                                              const float* __restrict__ Wa,
                                              const float* __restrict__ ba,
                                              const float* __restrict__ Wz,
                                              const float* __restrict__ bz,
                                              float* __restrict__ out) {
  __shared__ float hrow[256];
  __shared__ float red[256];
  int t = threadIdx.x;
  {
    int c = t & 127;
    hrow[t] = fmaxf(fmaf(bf2f(h[t]), ab[c], ab[128 + c]), 0.f);
  }
  __syncthreads();
  int j = t & 127, r = t >> 7;
  float acc = bh[j];
  for (int k = 0; k < 128; ++k)
    acc = fmaf(hrow[r * 128 + k], Wh[k * 128 + j], acc);
  float hv = fmaxf(acc, 0.f);
  float wv = (r == 0) ? Wa[j] : Wz[j];
  red[t] = hv * wv;
  __syncthreads();
  for (int s = 64; s >= 1; s >>= 1) {
    if (j < s) red[t] += red[t + s];
    __syncthreads();
  }
  if (t == 0) out[0] = red[0] + ba[0];
  if (t == 128) out[1] = red[128] + bz[0];
}

extern "C" void kernel_launch(void* const* d_in, const int* in_sizes, int n_in,
                              void* d_out, int out_size, void* d_ws, size_t ws_size,
                              hipStream_t stream) {
  const float* x  = (const float*)d_in[0];
  const int*   ei = (const int*)d_in[1];
  const float* ew = (const float*)d_in[2];
  const float* W[3]  = {(const float*)d_in[3], (const float*)d_in[5], (const float*)d_in[7]};
  // b1/b2/b3 cancel inside BatchNorm -> skipped.
  const float* g[3]  = {(const float*)d_in[9],  (const float*)d_in[11], (const float*)d_in[13]};
  const float* be[3] = {(const float*)d_in[10], (const float*)d_in[12], (const float*)d_in[14]};
  const float* Wh = (const float*)d_in[15];
  const float* bh = (const float*)d_in[16];
  const float* Wa = (const float*)d_in[17];
  const float* ba = (const float*)d_in[18];
  const float* Wz = (const float*)d_in[19];
  const float* bz = (const float*)d_in[20];

  const int n = in_sizes[0] / 128;
  const int e = in_sizes[1] / 2;
  const int* row = ei;
  const int* col = ei + e;

  u16*   hw_b   = (u16*)d_ws;
  u16*   hbuf_b = hw_b + (size_t)n * 128;
  float* dinv   = (float*)(hbuf_b + (size_t)n * 128);
  float* stats  = dinv + n;
  float* ab     = stats + 256;            // 3 * 256
  int*   cnt    = (int*)(ab + 3 * 256);
  int*   ptr    = cnt + n;
  int*   bsum   = ptr + n + 1;            // 256
  int*   rank   = bsum + 256;             // E
  uintptr_t pm  = ((uintptr_t)(rank + e) + 15) & ~(uintptr_t)15;
  int2*  emeta  = (int2*)pm;              // E

  const int nb_n = (n + 255) / 256;
  const int nb_e = (e + 255) / 256;

  k_zero_cnt<<<nb_n, 256, 0, stream>>>(cnt, n);
  k_count_rank<<<nb_e, 256, 0, stream>>>(col, cnt, rank, e);
  k_scan1<<<nb_n, 256, 0, stream>>>(cnt, ptr, bsum, n);
  k_scan2<<<1, 256, 0, stream>>>(bsum, nb_n);
  k_scan3<<<nb_n, 256, 0, stream>>>(ptr, bsum, n, e);
  k_fill<<<nb_e, 256, 0, stream>>>(row, col, ew, ptr, rank, emeta, e);
  k_deg_dinv<<<nb_n, 256, 0, stream>>>(ptr, emeta, dinv, n);
  k_coef<<<nb_n, 256, 0, stream>>>(ptr, emeta, dinv, n);

  for (int l = 0; l < 3; ++l) {
    const void* hin = (l == 0) ? (const void*)x : (const void*)hbuf_b;
    const float* abp = (l == 0) ? nullptr : (ab + (l - 1) * 256);
    k_gemm<<<(n + 127) / 128, 256, 0, stream>>>(hin, (l == 0) ? 1 : 0, W[l],
                                                hw_b, abp, n);
    k_gather<<<(n + 3) / 4, 256, 0, stream>>>(hw_b, ptr, emeta, dinv, hbuf_b,
                                              stats, n);
    k_bn_stats<<<512, 256, 0, stream>>>(hbuf_b, stats, n);
    k_bn_finalize<<<1, 128, 0, stream>>>(stats, g[l], be[l], ab + l * 256, n);
  }
  k_head<<<1, 256, 0, stream>>>(hbuf_b, ab + 2 * 256, Wh, bh, Wa, ba, Wz, bz,
                                (float*)d_out);
}